// Round 3
// baseline (901.514 us; speedup 1.0000x reference)
//
#include <hip/hip_runtime.h>
#include <hip/hip_bf16.h>
#include <cstdint>

#define L_SEQ 1024
#define HID_DIM 512
#define N_HEADS 8
#define HEAD_DIM 64
#define BATCH 8

// swizzle: insert 4-float pad every 32 floats (row length 128 -> 140)
__device__ __forceinline__ int swzc(int c) { return c + ((c >> 5) << 2); }

// out[m][n] = sum_k A[m][k] * W[n][k] + bias[n];  N = K = 512, M = 8192
__global__ __launch_bounds__(256)
void gemm512_bias(const float* __restrict__ A, const float* __restrict__ W,
                  const float* __restrict__ bias, float* __restrict__ out) {
  __shared__ float sA[16][140];
  __shared__ float sB[16][140];
  const int tid = threadIdx.x;
  const int m0 = blockIdx.x * 128, n0 = blockIdx.y * 128;
  const int tx = tid & 15, ty = tid >> 4;
  const int lr = tid >> 1, lk = (tid & 1) * 8;
  float acc[8][8] = {};
  const float* Ap = A + (size_t)(m0 + lr) * HID_DIM + lk;
  const float* Wp = W + (size_t)(n0 + lr) * HID_DIM + lk;
  for (int k0 = 0; k0 < HID_DIM; k0 += 16) {
    float4 a0 = *(const float4*)(Ap + k0);
    float4 a1 = *(const float4*)(Ap + k0 + 4);
    float4 b0 = *(const float4*)(Wp + k0);
    float4 b1 = *(const float4*)(Wp + k0 + 4);
    __syncthreads();
    const int sc = swzc(lr);
    sA[lk + 0][sc] = a0.x; sA[lk + 1][sc] = a0.y; sA[lk + 2][sc] = a0.z; sA[lk + 3][sc] = a0.w;
    sA[lk + 4][sc] = a1.x; sA[lk + 5][sc] = a1.y; sA[lk + 6][sc] = a1.z; sA[lk + 7][sc] = a1.w;
    sB[lk + 0][sc] = b0.x; sB[lk + 1][sc] = b0.y; sB[lk + 2][sc] = b0.z; sB[lk + 3][sc] = b0.w;
    sB[lk + 4][sc] = b1.x; sB[lk + 5][sc] = b1.y; sB[lk + 6][sc] = b1.z; sB[lk + 7][sc] = b1.w;
    __syncthreads();
#pragma unroll
    for (int kk = 0; kk < 16; ++kk) {
      float a[8], bv[8];
      *(float4*)&a[0]  = *(const float4*)&sA[kk][swzc(ty * 8)];
      *(float4*)&a[4]  = *(const float4*)&sA[kk][swzc(ty * 8) + 4];
      *(float4*)&bv[0] = *(const float4*)&sB[kk][swzc(tx * 8)];
      *(float4*)&bv[4] = *(const float4*)&sB[kk][swzc(tx * 8) + 4];
#pragma unroll
      for (int i = 0; i < 8; ++i)
#pragma unroll
        for (int j = 0; j < 8; ++j)
          acc[i][j] += a[i] * bv[j];
    }
  }
  float bv8[8];
  *(float4*)&bv8[0] = *(const float4*)&bias[n0 + tx * 8];
  *(float4*)&bv8[4] = *(const float4*)&bias[n0 + tx * 8 + 4];
#pragma unroll
  for (int i = 0; i < 8; ++i) {
    float4 o0, o1;
    o0.x = acc[i][0] + bv8[0]; o0.y = acc[i][1] + bv8[1];
    o0.z = acc[i][2] + bv8[2]; o0.w = acc[i][3] + bv8[3];
    o1.x = acc[i][4] + bv8[4]; o1.y = acc[i][5] + bv8[5];
    o1.z = acc[i][6] + bv8[6]; o1.w = acc[i][7] + bv8[7];
    float* orow = out + (size_t)(m0 + ty * 8 + i) * HID_DIM + n0 + tx * 8;
    *(float4*)orow = o0;
    *(float4*)(orow + 4) = o1;
  }
}

// lens[b] = number of un-padded rows in batch b. padding_mask may arrive as
// 1-byte bools OR as int32 (harness marshals "integer -> const int*").
// Detect layout from content over the first 8192 bytes (valid either way):
// byte layout has packed-pad words like 0x01010101 (>1); int32 layout has
// only values 0/1.
__global__ __launch_bounds__(256)
void lens_kernel(const uint8_t* __restrict__ pm, int* __restrict__ lens) {
  __shared__ int flag;
  __shared__ int part[256];
  const int b = blockIdx.x, tid = threadIdx.x;
  if (tid == 0) flag = 0;
  __syncthreads();
  const unsigned* pw = (const unsigned*)pm;
  unsigned any = 0;
  for (int i = tid; i < 2048; i += 256) any |= (pw[i] > 1u);
  if (any) flag = 1;
  __syncthreads();
  int c = 0;
  if (flag) {
    // byte layout: count zero bytes in pm[b*1024 .. b*1024+1023]
    unsigned v = pw[b * 256 + tid];
    c = (int)((v & 0xFFu) == 0) + (int)(((v >> 8) & 0xFFu) == 0) +
        (int)(((v >> 16) & 0xFFu) == 0) + (int)(((v >> 24) & 0xFFu) == 0);
  } else {
    // int32 layout: count zero words in pm_int32[b*1024 .. b*1024+1023]
    const int* pi = (const int*)pm;
    c = (int)(pi[b * 1024 + tid * 4 + 0] == 0) + (int)(pi[b * 1024 + tid * 4 + 1] == 0) +
        (int)(pi[b * 1024 + tid * 4 + 2] == 0) + (int)(pi[b * 1024 + tid * 4 + 3] == 0);
  }
  part[tid] = c;
  __syncthreads();
  for (int s = 128; s > 0; s >>= 1) {
    if (tid < s) part[tid] += part[tid + s];
    __syncthreads();
  }
  if (tid == 0) lens[b] = part[0];
}

// one thread per (b,h,q-row). q and O in registers, K/V tiles in LDS (broadcast reads).
__global__ __launch_bounds__(256)
void attn_kernel(const float* __restrict__ q_ws, const float* __restrict__ k_ws,
                 const float* __restrict__ v_ws, const int* __restrict__ tbm,
                 const float* __restrict__ time_emb, const int* __restrict__ lens,
                 float* __restrict__ a_ws) {
  __shared__ float ks[64][68];
  __shared__ float vs[64][68];
  __shared__ float te_s[8];
  const int tid = threadIdx.x;
  const int h = blockIdx.y, b = blockIdx.z;
  const int q0 = blockIdx.x * 256;
  const int qi = q0 + tid;
  const int len = lens[b];
  if (tid < 8) te_s[tid] = time_emb[tid * N_HEADS + h];

  float q[64];
  const float* qp = q_ws + ((size_t)b * L_SEQ + qi) * HID_DIM + h * HEAD_DIM;
#pragma unroll
  for (int d4 = 0; d4 < 16; ++d4)
    *(float4*)&q[d4 * 4] = *(const float4*)(qp + d4 * 4);

  float O[64];
#pragma unroll
  for (int d = 0; d < 64; ++d) O[d] = 0.f;
  float ssum = 0.f;

  const int jmax = (qi < len) ? qi : -1;  // causal: j<=qi; qi<len => qi<=len-1
  const int* tbrow = tbm + ((size_t)b * L_SEQ + qi) * L_SEQ;
  const int keyend = (q0 + 256 < len) ? q0 + 256 : len;  // block-uniform tile bound
  const int lrow = tid >> 2, lcol = (tid & 3) * 16;

  for (int kb = 0; kb < keyend; kb += 64) {
    const float* kp = k_ws + ((size_t)b * L_SEQ + kb + lrow) * HID_DIM + h * HEAD_DIM + lcol;
    const float* vp = v_ws + ((size_t)b * L_SEQ + kb + lrow) * HID_DIM + h * HEAD_DIM + lcol;
    float4 kr0 = *(const float4*)(kp);
    float4 kr1 = *(const float4*)(kp + 4);
    float4 kr2 = *(const float4*)(kp + 8);
    float4 kr3 = *(const float4*)(kp + 12);
    float4 vr0 = *(const float4*)(vp);
    float4 vr1 = *(const float4*)(vp + 4);
    float4 vr2 = *(const float4*)(vp + 8);
    float4 vr3 = *(const float4*)(vp + 12);
    __syncthreads();
    *(float4*)&ks[lrow][lcol + 0]  = kr0;
    *(float4*)&ks[lrow][lcol + 4]  = kr1;
    *(float4*)&ks[lrow][lcol + 8]  = kr2;
    *(float4*)&ks[lrow][lcol + 12] = kr3;
    *(float4*)&vs[lrow][lcol + 0]  = vr0;
    *(float4*)&vs[lrow][lcol + 4]  = vr1;
    *(float4*)&vs[lrow][lcol + 8]  = vr2;
    *(float4*)&vs[lrow][lcol + 12] = vr3;
    __syncthreads();

    int jrel = jmax - kb + 1;                 // #allowed keys in this tile (may be <=0)
    const int jend = jrel > 64 ? 64 : jrel;
    const int jfull = jend > 0 ? (jend & ~3) : 0;
    for (int j4 = 0; j4 < jfull; j4 += 4) {
      int4 tbv = *(const int4*)(tbrow + kb + j4);
#pragma unroll
      for (int u = 0; u < 4; ++u) {
        const int j = j4 + u;
        const int tb = (u == 0) ? tbv.x : (u == 1) ? tbv.y : (u == 2) ? tbv.z : tbv.w;
        float4 s4 = {0.f, 0.f, 0.f, 0.f};
        const float* kr = &ks[j][0];
#pragma unroll
        for (int d4 = 0; d4 < 16; ++d4) {
          float4 kv = *(const float4*)(kr + d4 * 4);
          s4.x += q[d4 * 4 + 0] * kv.x; s4.y += q[d4 * 4 + 1] * kv.y;
          s4.z += q[d4 * 4 + 2] * kv.z; s4.w += q[d4 * 4 + 3] * kv.w;
        }
        const float s = (s4.x + s4.y + s4.z + s4.w) * 0.125f + te_s[tb];
        const float p = __expf(s);
        ssum += p;
        const float* vr = &vs[j][0];
#pragma unroll
        for (int d4 = 0; d4 < 16; ++d4) {
          float4 vv = *(const float4*)(vr + d4 * 4);
          O[d4 * 4 + 0] += p * vv.x; O[d4 * 4 + 1] += p * vv.y;
          O[d4 * 4 + 2] += p * vv.z; O[d4 * 4 + 3] += p * vv.w;
        }
      }
    }
    for (int j = jfull; j < jend; ++j) {
      const int tb = tbrow[kb + j];
      float4 s4 = {0.f, 0.f, 0.f, 0.f};
      const float* kr = &ks[j][0];
#pragma unroll
      for (int d4 = 0; d4 < 16; ++d4) {
        float4 kv = *(const float4*)(kr + d4 * 4);
        s4.x += q[d4 * 4 + 0] * kv.x; s4.y += q[d4 * 4 + 1] * kv.y;
        s4.z += q[d4 * 4 + 2] * kv.z; s4.w += q[d4 * 4 + 3] * kv.w;
      }
      const float s = (s4.x + s4.y + s4.z + s4.w) * 0.125f + te_s[tb];
      const float p = __expf(s);
      ssum += p;
      const float* vr = &vs[j][0];
#pragma unroll
      for (int d4 = 0; d4 < 16; ++d4) {
        float4 vv = *(const float4*)(vr + d4 * 4);
        O[d4 * 4 + 0] += p * vv.x; O[d4 * 4 + 1] += p * vv.y;
        O[d4 * 4 + 2] += p * vv.z; O[d4 * 4 + 3] += p * vv.w;
      }
    }
  }

  const float inv = (jmax >= 0) ? 1.0f / ssum : 0.0f;  // query-pad rows -> exact 0
  float* op = a_ws + ((size_t)b * L_SEQ + qi) * HID_DIM + h * HEAD_DIM;
#pragma unroll
  for (int d4 = 0; d4 < 16; ++d4) {
    float4 o4;
    o4.x = O[d4 * 4 + 0] * inv; o4.y = O[d4 * 4 + 1] * inv;
    o4.z = O[d4 * 4 + 2] * inv; o4.w = O[d4 * 4 + 3] * inv;
    *(float4*)(op + d4 * 4) = o4;
  }
}

extern "C" void kernel_launch(void* const* d_in, const int* in_sizes, int n_in,
                              void* d_out, int out_size, void* d_ws, size_t ws_size,
                              hipStream_t stream) {
  const float* x    = (const float*)d_in[0];
  const int*   tbm  = (const int*)d_in[1];
  // d_in[2] = causal_mask: deterministic triu(k=1) -> handled analytically
  const uint8_t* pm = (const uint8_t*)d_in[3];
  const float* Wq = (const float*)d_in[4];
  const float* bq = (const float*)d_in[5];
  const float* Wk = (const float*)d_in[6];
  const float* bk = (const float*)d_in[7];
  const float* Wv = (const float*)d_in[8];
  const float* bv = (const float*)d_in[9];
  const float* Wo = (const float*)d_in[10];
  const float* bo = (const float*)d_in[11];
  const float* temb = (const float*)d_in[12];
  float* out = (float*)d_out;

  const size_t NTOK = (size_t)BATCH * L_SEQ * HID_DIM;  // 4,194,304 floats
  float* q_ws = (float*)d_ws;
  float* k_ws = q_ws + NTOK;
  float* v_ws = k_ws + NTOK;
  float* a_ws = v_ws + NTOK;
  int* lens   = (int*)(a_ws + NTOK);

  lens_kernel<<<8, 256, 0, stream>>>(pm, lens);
  dim3 gg(64, 4);
  gemm512_bias<<<gg, 256, 0, stream>>>(x, Wq, bq, q_ws);
  gemm512_bias<<<gg, 256, 0, stream>>>(x, Wk, bk, k_ws);
  gemm512_bias<<<gg, 256, 0, stream>>>(x, Wv, bv, v_ws);
  attn_kernel<<<dim3(4, N_HEADS, BATCH), 256, 0, stream>>>(q_ws, k_ws, v_ws, tbm, temb, lens, a_ws);
  gemm512_bias<<<gg, 256, 0, stream>>>(a_ws, Wo, bo, out);
}

// Round 4
// 336.521 us; speedup vs baseline: 2.6789x; 2.6789x over previous
//
#include <hip/hip_runtime.h>
#include <hip/hip_bf16.h>
#include <cstdint>

#define L_SEQ 1024
#define HID_DIM 512
#define N_HEADS 8
#define HEAD_DIM 64
#define BATCH 8

typedef __attribute__((ext_vector_type(8))) short bf16x8;
typedef __attribute__((ext_vector_type(4))) float f32x4;

__device__ __forceinline__ int swzc(int c) { return c + ((c >> 5) << 2); }

__device__ __forceinline__ ushort f2bf(float v) {
  __hip_bfloat16 hb = __float2bfloat16(v);
  return *(ushort*)&hb;
}

// out[m][n] = sum_k A[m][k] * W[n][k] + bias[n];  N = K = 512, M = 8192
// MODE 0: f32 row-major; MODE 1: bf16 row-major; MODE 2: bf16 transposed [b,h,d,key]
template <int MODE>
__global__ __launch_bounds__(256)
void gemm512_bias(const float* __restrict__ A, const float* __restrict__ W,
                  const float* __restrict__ bias, void* __restrict__ outv) {
  __shared__ float sA[16][140];
  __shared__ float sB[16][140];
  const int tid = threadIdx.x;
  const int m0 = blockIdx.x * 128, n0 = blockIdx.y * 128;
  const int tx = tid & 15, ty = tid >> 4;
  const int lr = tid >> 1, lk = (tid & 1) * 8;
  float acc[8][8] = {};
  const float* Ap = A + (size_t)(m0 + lr) * HID_DIM + lk;
  const float* Wp = W + (size_t)(n0 + lr) * HID_DIM + lk;
  for (int k0 = 0; k0 < HID_DIM; k0 += 16) {
    float4 a0 = *(const float4*)(Ap + k0);
    float4 a1 = *(const float4*)(Ap + k0 + 4);
    float4 b0 = *(const float4*)(Wp + k0);
    float4 b1 = *(const float4*)(Wp + k0 + 4);
    __syncthreads();
    const int sc = swzc(lr);
    sA[lk + 0][sc] = a0.x; sA[lk + 1][sc] = a0.y; sA[lk + 2][sc] = a0.z; sA[lk + 3][sc] = a0.w;
    sA[lk + 4][sc] = a1.x; sA[lk + 5][sc] = a1.y; sA[lk + 6][sc] = a1.z; sA[lk + 7][sc] = a1.w;
    sB[lk + 0][sc] = b0.x; sB[lk + 1][sc] = b0.y; sB[lk + 2][sc] = b0.z; sB[lk + 3][sc] = b0.w;
    sB[lk + 4][sc] = b1.x; sB[lk + 5][sc] = b1.y; sB[lk + 6][sc] = b1.z; sB[lk + 7][sc] = b1.w;
    __syncthreads();
#pragma unroll
    for (int kk = 0; kk < 16; ++kk) {
      float a[8], bv[8];
      *(float4*)&a[0]  = *(const float4*)&sA[kk][swzc(ty * 8)];
      *(float4*)&a[4]  = *(const float4*)&sA[kk][swzc(ty * 8) + 4];
      *(float4*)&bv[0] = *(const float4*)&sB[kk][swzc(tx * 8)];
      *(float4*)&bv[4] = *(const float4*)&sB[kk][swzc(tx * 8) + 4];
#pragma unroll
      for (int i = 0; i < 8; ++i)
#pragma unroll
        for (int j = 0; j < 8; ++j)
          acc[i][j] += a[i] * bv[j];
    }
  }
  float bv8[8];
  *(float4*)&bv8[0] = *(const float4*)&bias[n0 + tx * 8];
  *(float4*)&bv8[4] = *(const float4*)&bias[n0 + tx * 8 + 4];

  if (MODE == 0) {
    float* out = (float*)outv;
#pragma unroll
    for (int i = 0; i < 8; ++i) {
      float4 o0, o1;
      o0.x = acc[i][0] + bv8[0]; o0.y = acc[i][1] + bv8[1];
      o0.z = acc[i][2] + bv8[2]; o0.w = acc[i][3] + bv8[3];
      o1.x = acc[i][4] + bv8[4]; o1.y = acc[i][5] + bv8[5];
      o1.z = acc[i][6] + bv8[6]; o1.w = acc[i][7] + bv8[7];
      float* orow = out + (size_t)(m0 + ty * 8 + i) * HID_DIM + n0 + tx * 8;
      *(float4*)orow = o0;
      *(float4*)(orow + 4) = o1;
    }
  } else if (MODE == 1) {
    ushort* out = (ushort*)outv;
#pragma unroll
    for (int i = 0; i < 8; ++i) {
      ushort u[8];
#pragma unroll
      for (int j = 0; j < 8; ++j) u[j] = f2bf(acc[i][j] + bv8[j]);
      *(uint4*)(out + (size_t)(m0 + ty * 8 + i) * HID_DIM + n0 + tx * 8) = *(uint4*)u;
    }
  } else {
    // V transposed: out[((b*8+h)*64 + d)*1024 + key], key = row index within batch
    ushort* out = (ushort*)outv;
    const int bb = m0 >> 10;
    const int key0 = (m0 & 1023) + ty * 8;
#pragma unroll
    for (int j = 0; j < 8; ++j) {
      const int n = n0 + tx * 8 + j;
      const int hh = n >> 6, d = n & 63;
      ushort u[8];
#pragma unroll
      for (int i = 0; i < 8; ++i) u[i] = f2bf(acc[i][j] + bv8[j]);
      *(uint4*)(out + ((size_t)((bb * 8 + hh) * 64 + d)) * L_SEQ + key0) = *(uint4*)u;
    }
  }
}

// lens[b] = number of un-padded rows in batch b (layout-detecting; see round 3)
__global__ __launch_bounds__(256)
void lens_kernel(const uint8_t* __restrict__ pm, int* __restrict__ lens) {
  __shared__ int flag;
  __shared__ int part[256];
  const int b = blockIdx.x, tid = threadIdx.x;
  if (tid == 0) flag = 0;
  __syncthreads();
  const unsigned* pw = (const unsigned*)pm;
  unsigned any = 0;
  for (int i = tid; i < 2048; i += 256) any |= (pw[i] > 1u);
  if (any) flag = 1;
  __syncthreads();
  int c = 0;
  if (flag) {
    unsigned v = pw[b * 256 + tid];
    c = (int)((v & 0xFFu) == 0) + (int)(((v >> 8) & 0xFFu) == 0) +
        (int)(((v >> 16) & 0xFFu) == 0) + (int)(((v >> 24) & 0xFFu) == 0);
  } else {
    const int* pi = (const int*)pm;
    c = (int)(pi[b * 1024 + tid * 4 + 0] == 0) + (int)(pi[b * 1024 + tid * 4 + 1] == 0) +
        (int)(pi[b * 1024 + tid * 4 + 2] == 0) + (int)(pi[b * 1024 + tid * 4 + 3] == 0);
  }
  part[tid] = c;
  __syncthreads();
  for (int s = 128; s > 0; s >>= 1) {
    if (tid < s) part[tid] += part[tid + s];
    __syncthreads();
  }
  if (tid == 0) lens[b] = part[0];
}

// MFMA flash attention. Block = (batch, tile-pair); 8 waves = 8 heads.
// Each wave processes q-tiles {t, 63-t} (16 rows each) for its head.
// Layouts (mfma_f32_16x16x32_bf16): A: row=l&15, k=8*(l>>4)+i; B: col=l&15,
// k=8*(l>>4)+i; C/D: col=l&15, row=4*(l>>4)+reg  [m89-verified].
__global__ __launch_bounds__(512)
void attn_mfma(const ushort* __restrict__ qb, const ushort* __restrict__ kb,
               const ushort* __restrict__ vT, const int* __restrict__ tbm,
               const float* __restrict__ temb, const int* __restrict__ lens,
               float* __restrict__ a_ws) {
  __shared__ char pbuf[8][2048];  // per-wave P tile: 16 rows x 64 keys bf16, XOR-swizzled
  const int tid = threadIdx.x;
  const int w = tid >> 6;          // wave index = head
  const int lane = tid & 63;
  const int l15 = lane & 15, g = lane >> 4;
  const int b = blockIdx.x;        // batch (XCD-major for L2 locality)
  const int tp = blockIdx.y;       // tile-pair 0..31
  const int h = w;
  const int len = lens[b];

  // lane (i&7) holds time_emb[i&7][h] * log2(e)  (for ds_bpermute lookup)
  const float te_src = temb[(lane & 7) * N_HEADS + h] * 1.44269504f;

#pragma unroll 1
  for (int tsel = 0; tsel < 2; ++tsel) {
    const int t = (tsel == 0) ? tp : (63 - tp);
    const int qbase = t * 16;

    // Q fragments (A-operand), d-blocks 0/1
    bf16x8 qf[2];
    {
      const ushort* qrow = qb + (size_t)(b * L_SEQ + qbase + l15) * HID_DIM + h * HEAD_DIM + 8 * g;
      qf[0] = *(const bf16x8*)(qrow);
      qf[1] = *(const bf16x8*)(qrow + 32);
    }

    f32x4 O[4];  // output col-tiles ct=0..3 (d = 16*ct + l15)
#pragma unroll
    for (int ct = 0; ct < 4; ++ct) O[ct] = (f32x4){0.f, 0.f, 0.f, 0.f};
    float ssum[4] = {0.f, 0.f, 0.f, 0.f};  // per reg r (row 4g+r), partial over cols l15

    const int ke = (qbase + 16 < len) ? (qbase + 16) : len;
    const int nch = (qbase < len) ? ((ke + 63) >> 6) : 0;

    for (int c = 0; c < nch; ++c) {
      const int kc = c * 64;
      // K fragments (B-operand): 4 key-tiles x 2 d-blocks
      bf16x8 kf[4][2];
#pragma unroll
      for (int kt = 0; kt < 4; ++kt) {
        const ushort* krow = kb + (size_t)(b * L_SEQ + kc + 16 * kt + l15) * HID_DIM + h * HEAD_DIM + 8 * g;
        kf[kt][0] = *(const bf16x8*)(krow);
        kf[kt][1] = *(const bf16x8*)(krow + 32);
      }
      // V fragments (B-operand for PV): 2 key-blocks x 4 d-col-tiles
      bf16x8 vf[2][4];
#pragma unroll
      for (int kblk = 0; kblk < 2; ++kblk)
#pragma unroll
        for (int ct = 0; ct < 4; ++ct) {
          const ushort* vrow = vT + (size_t)((b * 8 + h) * 64 + 16 * ct + l15) * L_SEQ + kc + 32 * kblk + 8 * g;
          vf[kblk][ct] = *(const bf16x8*)(vrow);
        }

      const int* tbq = tbm + (size_t)(b * L_SEQ + qbase) * L_SEQ + kc;

#pragma unroll
      for (int kt = 0; kt < 4; ++kt) {
        f32x4 s = (f32x4){0.f, 0.f, 0.f, 0.f};
        s = __builtin_amdgcn_mfma_f32_16x16x32_bf16(qf[0], kf[kt][0], s, 0, 0, 0);
        s = __builtin_amdgcn_mfma_f32_16x16x32_bf16(qf[1], kf[kt][1], s, 0, 0, 0);
        const int kg = kc + 16 * kt + l15;
#pragma unroll
        for (int r = 0; r < 4; ++r) {
          const int lr = 4 * g + r;          // local row
          const int qg = qbase + lr;         // global q row
          const int tb = tbq[lr * L_SEQ + 16 * kt + l15];
          const float te2 = __int_as_float(
              __builtin_amdgcn_ds_bpermute(tb << 2, __float_as_int(te_src)));
          float p = exp2f(fmaf(s[r], 0.18033688f, te2));
          p = (kg <= qg && qg < len) ? p : 0.0f;
          const ushort pbits = f2bf(p);
          __hip_bfloat162 tmp; // consistent f32 value of the bf16 weight
          ssum[r] += __bfloat162float(*(const __hip_bfloat16*)&pbits);
          const int off = ((lr * 128 + (16 * kt + l15) * 2) ^ ((lr & 7) << 4));
          *(ushort*)&pbuf[w][off] = pbits;
          (void)tmp;
        }
      }
      // PV: O[ct] += P(16x64) * V(64x64)
#pragma unroll
      for (int kblk = 0; kblk < 2; ++kblk) {
        const int off = ((l15 * 128 + kblk * 64 + 16 * g) ^ ((l15 & 7) << 4));
        const bf16x8 pf = *(const bf16x8*)(&pbuf[w][off]);
#pragma unroll
        for (int ct = 0; ct < 4; ++ct)
          O[ct] = __builtin_amdgcn_mfma_f32_16x16x32_bf16(pf, vf[kblk][ct], O[ct], 0, 0, 0);
      }
    }

    // row-sum reduce across the 16 cols held by lanes (same 4g+r rows share g)
#pragma unroll
    for (int m = 1; m <= 8; m <<= 1) {
#pragma unroll
      for (int r = 0; r < 4; ++r) ssum[r] += __shfl_xor(ssum[r], m, 64);
    }
    float inv[4];
#pragma unroll
    for (int r = 0; r < 4; ++r) {
      const int qg = qbase + 4 * g + r;
      inv[r] = (qg < len) ? 1.0f / ssum[r] : 0.0f;
    }
    // epilogue: a_ws[b, qg, h*64 + 16*ct + l15] = O[ct][r] * inv[r]
#pragma unroll
    for (int ct = 0; ct < 4; ++ct)
#pragma unroll
      for (int r = 0; r < 4; ++r) {
        const int qg = qbase + 4 * g + r;
        a_ws[(size_t)(b * L_SEQ + qg) * HID_DIM + h * HEAD_DIM + 16 * ct + l15] = O[ct][r] * inv[r];
      }
  }
}

extern "C" void kernel_launch(void* const* d_in, const int* in_sizes, int n_in,
                              void* d_out, int out_size, void* d_ws, size_t ws_size,
                              hipStream_t stream) {
  const float* x    = (const float*)d_in[0];
  const int*   tbm  = (const int*)d_in[1];
  // d_in[2] = causal_mask: deterministic triu(k=1) -> handled analytically
  const uint8_t* pm = (const uint8_t*)d_in[3];
  const float* Wq = (const float*)d_in[4];
  const float* bq = (const float*)d_in[5];
  const float* Wk = (const float*)d_in[6];
  const float* bk = (const float*)d_in[7];
  const float* Wv = (const float*)d_in[8];
  const float* bv = (const float*)d_in[9];
  const float* Wo = (const float*)d_in[10];
  const float* bo = (const float*)d_in[11];
  const float* temb = (const float*)d_in[12];
  float* out = (float*)d_out;

  const size_t NTOK = (size_t)BATCH * L_SEQ * HID_DIM;  // 4,194,304 elements
  float*  a_ws = (float*)d_ws;                    // f32 attn output
  ushort* qb   = (ushort*)(a_ws + NTOK);          // bf16 Q [token][hid]
  ushort* kb   = qb + NTOK;                       // bf16 K [token][hid]
  ushort* vT   = kb + NTOK;                       // bf16 V^T [b][h][d][key]
  int* lens    = (int*)(vT + NTOK);

  lens_kernel<<<8, 256, 0, stream>>>(pm, lens);
  dim3 gg(64, 4);
  gemm512_bias<1><<<gg, 256, 0, stream>>>(x, Wq, bq, qb);
  gemm512_bias<1><<<gg, 256, 0, stream>>>(x, Wk, bk, kb);
  gemm512_bias<2><<<gg, 256, 0, stream>>>(x, Wv, bv, vT);
  attn_mfma<<<dim3(8, 32), 512, 0, stream>>>(qb, kb, vT, tbm, temb, lens, a_ws);
  gemm512_bias<0><<<gg, 256, 0, stream>>>(a_ws, Wo, bo, out);
}

// Round 5
// 161.824 us; speedup vs baseline: 5.5709x; 2.0795x over previous
//
#include <hip/hip_runtime.h>
#include <hip/hip_bf16.h>
#include <cstdint>

#define L_SEQ 1024
#define HID_DIM 512
#define N_HEADS 8
#define HEAD_DIM 64
#define BATCH 8

typedef __attribute__((ext_vector_type(8))) short bf16x8;
typedef __attribute__((ext_vector_type(4))) float f32x4;

__device__ __forceinline__ ushort f2bf(float v) {
  __hip_bfloat16 hb = __float2bfloat16(v);
  return *(ushort*)&hb;
}

// Convert f32 -> bf16: x (4,194,304) then Wq,Wk,Wv,Wo (262,144 each) into one
// contiguous bf16 buffer. 8 elems/thread.
__global__ __launch_bounds__(256)
void prep_convert(const float* __restrict__ x, const float* __restrict__ Wq,
                  const float* __restrict__ Wk, const float* __restrict__ Wv,
                  const float* __restrict__ Wo, ushort* __restrict__ dst) {
  const size_t gid = (size_t)blockIdx.x * 256 + threadIdx.x;
  const size_t e = gid * 8;
  const float* src;
  size_t loc;
  if (e < 4194304) {
    src = x; loc = e;
  } else {
    const size_t r = e - 4194304;
    const int wsel = (int)(r >> 18);
    loc = r & 262143;
    src = (wsel == 0) ? Wq : (wsel == 1) ? Wk : (wsel == 2) ? Wv : Wo;
  }
  float4 v0 = *(const float4*)(src + loc);
  float4 v1 = *(const float4*)(src + loc + 4);
  ushort u[8];
  u[0] = f2bf(v0.x); u[1] = f2bf(v0.y); u[2] = f2bf(v0.z); u[3] = f2bf(v0.w);
  u[4] = f2bf(v1.x); u[5] = f2bf(v1.y); u[6] = f2bf(v1.z); u[7] = f2bf(v1.w);
  *(uint4*)(dst + e) = *(uint4*)u;
}

// lens[b] = number of un-padded rows in batch b (layout-detecting; see round 3)
__global__ __launch_bounds__(256)
void lens_kernel(const uint8_t* __restrict__ pm, int* __restrict__ lens) {
  __shared__ int flag;
  __shared__ int part[256];
  const int b = blockIdx.x, tid = threadIdx.x;
  if (tid == 0) flag = 0;
  __syncthreads();
  const unsigned* pw = (const unsigned*)pm;
  unsigned any = 0;
  for (int i = tid; i < 2048; i += 256) any |= (pw[i] > 1u);
  if (any) flag = 1;
  __syncthreads();
  int c = 0;
  if (flag) {
    unsigned v = pw[b * 256 + tid];
    c = (int)((v & 0xFFu) == 0) + (int)(((v >> 8) & 0xFFu) == 0) +
        (int)(((v >> 16) & 0xFFu) == 0) + (int)(((v >> 24) & 0xFFu) == 0);
  } else {
    const int* pi = (const int*)pm;
    c = (int)(pi[b * 1024 + tid * 4 + 0] == 0) + (int)(pi[b * 1024 + tid * 4 + 1] == 0) +
        (int)(pi[b * 1024 + tid * 4 + 2] == 0) + (int)(pi[b * 1024 + tid * 4 + 3] == 0);
  }
  part[tid] = c;
  __syncthreads();
  for (int s = 128; s > 0; s >>= 1) {
    if (tid < s) part[tid] += part[tid + s];
    __syncthreads();
  }
  if (tid == 0) lens[b] = part[0];
}

// MFMA GEMM: C[m][n] = sum_k A[m][k]*B[n][k] (+bias), K=512, both operands
// row-major bf16 K-contiguous. One wave per block; 64x64 tile = 4x4 MFMA frags.
// MODE 0: out bf16 row-major [m][512], bias[n]   (Q/K projections)
// MODE 1: out bf16 vT layout (A=Wv so m=hid, n=token), bias[m]
// MODE 2: out f32 row-major [m][512], bias[n]    (final projection)
// Fragment layouts per m89-verified mapping (validated by round-4 attention).
template <int MODE>
__global__ __launch_bounds__(64)
void mfma_gemm(const ushort* __restrict__ A, const ushort* __restrict__ B,
               const float* __restrict__ bias, void* __restrict__ outv) {
  const int lane = threadIdx.x;
  const int l15 = lane & 15, g = lane >> 4;
  const int M0 = ((MODE == 1) ? blockIdx.y : blockIdx.x) * 64;
  const int N0 = ((MODE == 1) ? blockIdx.x : blockIdx.y) * 64;

  const ushort* Abase = A + (size_t)(M0 + l15) * 512 + 8 * g;
  const ushort* Bbase = B + (size_t)(N0 + l15) * 512 + 8 * g;

  f32x4 acc[4][4];
#pragma unroll
  for (int i = 0; i < 4; ++i)
#pragma unroll
    for (int j = 0; j < 4; ++j) acc[i][j] = (f32x4){0.f, 0.f, 0.f, 0.f};

  bf16x8 aA[4], bA[4], aB[4], bB[4];

#define LOAD_FRAGS(av, bv, ks)                                              \
  {                                                                         \
    _Pragma("unroll") for (int t = 0; t < 4; ++t) {                         \
      av[t] = *(const bf16x8*)(Abase + (size_t)t * 16 * 512 + (ks) * 32);   \
      bv[t] = *(const bf16x8*)(Bbase + (size_t)t * 16 * 512 + (ks) * 32);   \
    }                                                                       \
  }
#define DO_MFMA(av, bv)                                                     \
  {                                                                         \
    _Pragma("unroll") for (int i = 0; i < 4; ++i)                           \
        _Pragma("unroll") for (int j = 0; j < 4; ++j) acc[i][j] =           \
            __builtin_amdgcn_mfma_f32_16x16x32_bf16(av[i], bv[j],           \
                                                    acc[i][j], 0, 0, 0);    \
  }

  LOAD_FRAGS(aA, bA, 0);
  LOAD_FRAGS(aB, bB, 1);
#pragma unroll
  for (int ks = 0; ks < 16; ks += 2) {
    DO_MFMA(aA, bA);
    if (ks + 2 < 16) LOAD_FRAGS(aA, bA, ks + 2);
    DO_MFMA(aB, bB);
    if (ks + 3 < 16) LOAD_FRAGS(aB, bB, ks + 3);
  }
#undef LOAD_FRAGS
#undef DO_MFMA

  if (MODE == 0 || MODE == 2) {
    float bn[4];
#pragma unroll
    for (int nt = 0; nt < 4; ++nt) bn[nt] = bias[N0 + nt * 16 + l15];
#pragma unroll
    for (int mt = 0; mt < 4; ++mt)
#pragma unroll
      for (int nt = 0; nt < 4; ++nt)
#pragma unroll
        for (int r = 0; r < 4; ++r) {
          const int m = M0 + mt * 16 + 4 * g + r;
          const int n = N0 + nt * 16 + l15;
          const float v = acc[mt][nt][r] + bn[nt];
          if (MODE == 0)
            ((ushort*)outv)[(size_t)m * 512 + n] = f2bf(v);
          else
            ((float*)outv)[(size_t)m * 512 + n] = v;
        }
  } else {
    // MODE 1: m = hid index of V, n = token. vT[((tok>>10)*512 + m)*1024 + (tok&1023)]
    ushort* out = (ushort*)outv;
#pragma unroll
    for (int mt = 0; mt < 4; ++mt)
#pragma unroll
      for (int r = 0; r < 4; ++r) {
        const int m = M0 + mt * 16 + 4 * g + r;
        const float bm = bias[m];
#pragma unroll
        for (int nt = 0; nt < 4; ++nt) {
          const int tok = N0 + nt * 16 + l15;
          const size_t off = ((size_t)((tok >> 10) * 512 + m)) * 1024 + (tok & 1023);
          out[off] = f2bf(acc[mt][nt][r] + bm);
        }
      }
  }
}

// MFMA flash attention (validated round 4). Epilogue now writes bf16.
__global__ __launch_bounds__(512)
void attn_mfma(const ushort* __restrict__ qb, const ushort* __restrict__ kb,
               const ushort* __restrict__ vT, const int* __restrict__ tbm,
               const float* __restrict__ temb, const int* __restrict__ lens,
               ushort* __restrict__ ab) {
  __shared__ char pbuf[8][2048];
  const int tid = threadIdx.x;
  const int w = tid >> 6;
  const int lane = tid & 63;
  const int l15 = lane & 15, g = lane >> 4;
  const int b = blockIdx.x;
  const int tp = blockIdx.y;
  const int h = w;
  const int len = lens[b];

  const float te_src = temb[(lane & 7) * N_HEADS + h] * 1.44269504f;

#pragma unroll 1
  for (int tsel = 0; tsel < 2; ++tsel) {
    const int t = (tsel == 0) ? tp : (63 - tp);
    const int qbase = t * 16;

    bf16x8 qf[2];
    {
      const ushort* qrow = qb + (size_t)(b * L_SEQ + qbase + l15) * HID_DIM + h * HEAD_DIM + 8 * g;
      qf[0] = *(const bf16x8*)(qrow);
      qf[1] = *(const bf16x8*)(qrow + 32);
    }

    f32x4 O[4];
#pragma unroll
    for (int ct = 0; ct < 4; ++ct) O[ct] = (f32x4){0.f, 0.f, 0.f, 0.f};
    float ssum[4] = {0.f, 0.f, 0.f, 0.f};

    const int ke = (qbase + 16 < len) ? (qbase + 16) : len;
    const int nch = (qbase < len) ? ((ke + 63) >> 6) : 0;

    for (int c = 0; c < nch; ++c) {
      const int kc = c * 64;
      bf16x8 kf[4][2];
#pragma unroll
      for (int kt = 0; kt < 4; ++kt) {
        const ushort* krow = kb + (size_t)(b * L_SEQ + kc + 16 * kt + l15) * HID_DIM + h * HEAD_DIM + 8 * g;
        kf[kt][0] = *(const bf16x8*)(krow);
        kf[kt][1] = *(const bf16x8*)(krow + 32);
      }
      bf16x8 vf[2][4];
#pragma unroll
      for (int kblk = 0; kblk < 2; ++kblk)
#pragma unroll
        for (int ct = 0; ct < 4; ++ct) {
          const ushort* vrow = vT + (size_t)((b * 8 + h) * 64 + 16 * ct + l15) * L_SEQ + kc + 32 * kblk + 8 * g;
          vf[kblk][ct] = *(const bf16x8*)(vrow);
        }

      const int* tbq = tbm + (size_t)(b * L_SEQ + qbase) * L_SEQ + kc;

#pragma unroll
      for (int kt = 0; kt < 4; ++kt) {
        f32x4 s = (f32x4){0.f, 0.f, 0.f, 0.f};
        s = __builtin_amdgcn_mfma_f32_16x16x32_bf16(qf[0], kf[kt][0], s, 0, 0, 0);
        s = __builtin_amdgcn_mfma_f32_16x16x32_bf16(qf[1], kf[kt][1], s, 0, 0, 0);
        const int kg = kc + 16 * kt + l15;
#pragma unroll
        for (int r = 0; r < 4; ++r) {
          const int lr = 4 * g + r;
          const int qg = qbase + lr;
          const int tb = tbq[lr * L_SEQ + 16 * kt + l15];
          const float te2 = __int_as_float(
              __builtin_amdgcn_ds_bpermute(tb << 2, __float_as_int(te_src)));
          float p = exp2f(fmaf(s[r], 0.18033688f, te2));
          p = (kg <= qg && qg < len) ? p : 0.0f;
          const ushort pbits = f2bf(p);
          ssum[r] += __bfloat162float(*(const __hip_bfloat16*)&pbits);
          const int off = ((lr * 128 + (16 * kt + l15) * 2) ^ ((lr & 7) << 4));
          *(ushort*)&pbuf[w][off] = pbits;
        }
      }
#pragma unroll
      for (int kblk = 0; kblk < 2; ++kblk) {
        const int off = ((l15 * 128 + kblk * 64 + 16 * g) ^ ((l15 & 7) << 4));
        const bf16x8 pf = *(const bf16x8*)(&pbuf[w][off]);
#pragma unroll
        for (int ct = 0; ct < 4; ++ct)
          O[ct] = __builtin_amdgcn_mfma_f32_16x16x32_bf16(pf, vf[kblk][ct], O[ct], 0, 0, 0);
      }
    }

#pragma unroll
    for (int m = 1; m <= 8; m <<= 1) {
#pragma unroll
      for (int r = 0; r < 4; ++r) ssum[r] += __shfl_xor(ssum[r], m, 64);
    }
    float inv[4];
#pragma unroll
    for (int r = 0; r < 4; ++r) {
      const int qg = qbase + 4 * g + r;
      inv[r] = (qg < len) ? 1.0f / ssum[r] : 0.0f;
    }
#pragma unroll
    for (int ct = 0; ct < 4; ++ct)
#pragma unroll
      for (int r = 0; r < 4; ++r) {
        const int qg = qbase + 4 * g + r;
        ab[(size_t)(b * L_SEQ + qg) * HID_DIM + h * HEAD_DIM + 16 * ct + l15] =
            f2bf(O[ct][r] * inv[r]);
      }
  }
}

extern "C" void kernel_launch(void* const* d_in, const int* in_sizes, int n_in,
                              void* d_out, int out_size, void* d_ws, size_t ws_size,
                              hipStream_t stream) {
  const float* x    = (const float*)d_in[0];
  const int*   tbm  = (const int*)d_in[1];
  // d_in[2] = causal_mask: deterministic triu(k=1) -> handled analytically
  const uint8_t* pm = (const uint8_t*)d_in[3];
  const float* Wq = (const float*)d_in[4];
  const float* bq = (const float*)d_in[5];
  const float* Wk = (const float*)d_in[6];
  const float* bk = (const float*)d_in[7];
  const float* Wv = (const float*)d_in[8];
  const float* bv = (const float*)d_in[9];
  const float* Wo = (const float*)d_in[10];
  const float* bo = (const float*)d_in[11];
  const float* temb = (const float*)d_in[12];
  float* out = (float*)d_out;

  const size_t NTOK = (size_t)BATCH * L_SEQ * HID_DIM;  // 4,194,304
  const size_t NW = 262144;
  ushort* ab  = (ushort*)d_ws;        // bf16 attention output [8192][512]
  ushort* xb  = ab + NTOK;            // bf16 x
  ushort* wqb = xb + NTOK;
  ushort* wkb = wqb + NW;
  ushort* wvb = wkb + NW;
  ushort* wob = wvb + NW;
  ushort* qb  = wob + NW;             // bf16 Q [tok][512]
  ushort* kb  = qb + NTOK;            // bf16 K [tok][512]
  ushort* vT  = kb + NTOK;            // bf16 V^T [b*8+h][64][1024]
  int* lens   = (int*)(vT + NTOK);

  prep_convert<<<2560, 256, 0, stream>>>(x, Wq, Wk, Wv, Wo, xb);
  lens_kernel<<<8, 256, 0, stream>>>(pm, lens);
  dim3 gg(128, 8);
  mfma_gemm<0><<<gg, 64, 0, stream>>>(xb, wqb, bq, qb);
  mfma_gemm<0><<<gg, 64, 0, stream>>>(xb, wkb, bk, kb);
  mfma_gemm<1><<<gg, 64, 0, stream>>>(wvb, xb, bv, vT);
  attn_mfma<<<dim3(8, 32), 512, 0, stream>>>(qb, kb, vT, tbm, temb, lens, ab);
  mfma_gemm<2><<<gg, 64, 0, stream>>>(ab, wob, bo, out);
}